// Round 7
// baseline (2171.756 us; speedup 1.0000x reference)
//
#include <hip/hip_runtime.h>
#include <cstdint>
#include <cmath>

typedef __bf16 bf16_t;
typedef __bf16 bf16x8 __attribute__((ext_vector_type(8)));
typedef __bf16 bf16x4 __attribute__((ext_vector_type(4)));
typedef float floatx4 __attribute__((ext_vector_type(4)));

#define DMODEL 768
#define NHEAD  12
#define SEQ    1024
#define NBATCH 4
#define ROWS   (NBATCH*SEQ)   // 4096
#define DH     (DMODEL*NHEAD) // 9216
#define DFF    (4*DMODEL)     // 3072

// ---------------------------------------------------------------------------
// GEMM: C = alpha*(A @ B^T) [+bias[col]] [relu] [+res]   (fp32 bias/res/out)
// A: M x K (lda) bf16, BT: N x K (ldb) bf16, C: M x N (ldc). fp32 accum.
// OMODE: 0 = bf16 store, 1 = f32 store, 2 = f32 accumulate
// Batched via blockIdx.z: off = (z/bdiv)*hi + (z%bdiv)*lo  (element offsets)
// 128x128 tile, BK=32, 4 waves x (4x4) 16x16x32 MFMA. LDS frag-ordered:
// block i (16 rows x 32 cols) at i*512 elems, lane-ordered so ds_read_b128 at
// (blk*512 + lane*8) is exactly one MFMA fragment (A[m=lane&15][k=(lane>>4)*8+j]).
// ---------------------------------------------------------------------------
template<bool BIAS, bool RES, bool RELU, int OMODE>
__global__ __launch_bounds__(256)
void gemm_bt(const bf16_t* __restrict__ A, const bf16_t* __restrict__ BT,
             void* __restrict__ Cv, int K, int lda, int ldb, int ldc,
             int bdiv, long sa_hi, long sa_lo, long sb_hi, long sb_lo,
             long sc_hi, long sc_lo,
             const float* __restrict__ bias, const float* __restrict__ res,
             int ldres, float alpha)
{
  __shared__ __align__(16) bf16_t As[128*32];
  __shared__ __align__(16) bf16_t Bs[128*32];

  const int tid  = threadIdx.x;
  const int wave = tid >> 6;
  const int lane = tid & 63;
  const int r    = lane & 15;   // row within 16-tile
  const int q    = lane >> 4;   // k-chunk (8 elems each)

  const int z = blockIdx.z;
  A  += (long)(z / bdiv) * sa_hi + (long)(z % bdiv) * sa_lo;
  BT += (long)(z / bdiv) * sb_hi + (long)(z % bdiv) * sb_lo;
  const long coff = (long)(z / bdiv) * sc_hi + (long)(z % bdiv) * sc_lo;

  const int bm = blockIdx.y * 128;
  const int bn = blockIdx.x * 128;
  const int wm = (wave & 1) * 64;
  const int wn = (wave >> 1) * 64;

  const int blk0 = 2*wave, blk1 = 2*wave + 1;
  const bf16_t* a_src0 = A  + (long)(bm + blk0*16 + r) * lda + q*8;
  const bf16_t* a_src1 = A  + (long)(bm + blk1*16 + r) * lda + q*8;
  const bf16_t* b_src0 = BT + (long)(bn + blk0*16 + r) * ldb + q*8;
  const bf16_t* b_src1 = BT + (long)(bn + blk1*16 + r) * ldb + q*8;
  bf16_t* a_dst0 = As + blk0*512 + lane*8;
  bf16_t* a_dst1 = As + blk1*512 + lane*8;
  bf16_t* b_dst0 = Bs + blk0*512 + lane*8;
  bf16_t* b_dst1 = Bs + blk1*512 + lane*8;

  const int am = (wave & 1) * 4;
  const int bb = (wave >> 1) * 4;

  floatx4 acc[4][4] = {};

  for (int k0 = 0; k0 < K; k0 += 32) {
    bf16x8 av0 = *(const bf16x8*)(a_src0 + k0);
    bf16x8 av1 = *(const bf16x8*)(a_src1 + k0);
    bf16x8 bv0 = *(const bf16x8*)(b_src0 + k0);
    bf16x8 bv1 = *(const bf16x8*)(b_src1 + k0);
    *(bf16x8*)a_dst0 = av0;
    *(bf16x8*)a_dst1 = av1;
    *(bf16x8*)b_dst0 = bv0;
    *(bf16x8*)b_dst1 = bv1;
    __syncthreads();
    bf16x8 afrag[4], bfrag[4];
#pragma unroll
    for (int t = 0; t < 4; ++t) {
      afrag[t] = *(const bf16x8*)(As + (am + t)*512 + lane*8);
      bfrag[t] = *(const bf16x8*)(Bs + (bb + t)*512 + lane*8);
    }
#pragma unroll
    for (int mt = 0; mt < 4; ++mt)
#pragma unroll
      for (int nt = 0; nt < 4; ++nt)
        acc[mt][nt] = __builtin_amdgcn_mfma_f32_16x16x32_bf16(
            afrag[mt], bfrag[nt], acc[mt][nt], 0, 0, 0);
    __syncthreads();
  }

  // epilogue: C/D layout col=lane&15, row=(lane>>4)*4+e
  const int row0 = bm + wm + q*4;
  const int col0 = bn + wn + r;
#pragma unroll
  for (int nt = 0; nt < 4; ++nt) {
    const int col = col0 + nt*16;
    float bv = 0.f;
    if (BIAS) bv = bias[col];
#pragma unroll
    for (int mt = 0; mt < 4; ++mt) {
#pragma unroll
      for (int e = 0; e < 4; ++e) {
        const int rowi = row0 + mt*16 + e;
        float v = acc[mt][nt][e] * alpha;
        if (BIAS) v += bv;
        if (RELU) v = fmaxf(v, 0.f);
        if (RES)  v += res[(long)rowi * ldres + col];
        const long idx = coff + (long)rowi * ldc + col;
        if (OMODE == 0)      ((bf16_t*)Cv)[idx] = (bf16_t)v;
        else if (OMODE == 1) ((float*)Cv)[idx] = v;
        else                 ((float*)Cv)[idx] += v;
      }
    }
  }
}

// -------- 32x32 tiled transpose, fp32 in -> bf16 out: out[c][r] = bf16(in[r][c]) --------
__global__ void transpose_f2b(const float* __restrict__ in, bf16_t* __restrict__ out,
                              int ldi, int ldo)
{
  __shared__ bf16_t tile[32][34];
  const int c0 = blockIdx.x * 32, r0 = blockIdx.y * 32;
  const int tx = threadIdx.x, ty = threadIdx.y;
#pragma unroll
  for (int i = 0; i < 4; ++i)
    tile[ty + 8*i][tx] = (bf16_t)in[(long)(r0 + ty + 8*i) * ldi + c0 + tx];
  __syncthreads();
#pragma unroll
  for (int i = 0; i < 4; ++i)
    out[(long)(c0 + ty + 8*i) * ldo + r0 + tx] = tile[tx][ty + 8*i];
}

// -------- batched 32x32 tiled transpose, bf16 -> bf16 (V -> Vt) --------
__global__ void transpose_b(const bf16_t* __restrict__ in, bf16_t* __restrict__ out,
                            int ldi, int ldo, int bdiv,
                            long si_hi, long si_lo, long so_hi, long so_lo)
{
  __shared__ bf16_t tile[32][34];
  const int z = blockIdx.z;
  in  += (long)(z / bdiv) * si_hi + (long)(z % bdiv) * si_lo;
  out += (long)(z / bdiv) * so_hi + (long)(z % bdiv) * so_lo;
  const int c0 = blockIdx.x * 32, r0 = blockIdx.y * 32;
  const int tx = threadIdx.x, ty = threadIdx.y;
#pragma unroll
  for (int i = 0; i < 4; ++i)
    tile[ty + 8*i][tx] = in[(long)(r0 + ty + 8*i) * ldi + c0 + tx];
  __syncthreads();
#pragma unroll
  for (int i = 0; i < 4; ++i)
    out[(long)(c0 + ty + 8*i) * ldo + r0 + tx] = tile[tx][ty + 8*i];
}

// -------- per-head weight transposes (fp32 -> bf16): z=0..2 WhT slices, z=3 WuTh --------
__global__ void transpose_wh(const float* __restrict__ Wq, const float* __restrict__ Wk,
                             const float* __restrict__ Wv, const float* __restrict__ Wu,
                             bf16_t* __restrict__ WhT, bf16_t* __restrict__ WuTh, int h)
{
  __shared__ bf16_t tile[32][34];
  const int z = blockIdx.z;
  const float* in; bf16_t* out; int ldi;
  if (z < 3) {
    const float* W = (z == 0) ? Wq : (z == 1) ? Wk : Wv;
    in  = W + (long)h * DMODEL;            // 768x768 column slice, ldi = DH
    ldi = DH;
    out = WhT + (long)z * DMODEL * DMODEL;
  } else {
    in  = Wu + (long)h * DMODEL * DMODEL;  // 768x768 row slice
    ldi = DMODEL;
    out = WuTh;
  }
  const int c0 = blockIdx.x * 32, r0 = blockIdx.y * 32;
  const int tx = threadIdx.x, ty = threadIdx.y;
#pragma unroll
  for (int i = 0; i < 4; ++i)
    tile[ty + 8*i][tx] = (bf16_t)in[(long)(r0 + ty + 8*i) * ldi + c0 + tx];
  __syncthreads();
#pragma unroll
  for (int i = 0; i < 4; ++i)
    out[(long)(c0 + ty + 8*i) * DMODEL + r0 + tx] = tile[tx][ty + 8*i];
}

// ---------------- LayerNorm over last dim (768): fp32 in -> bf16 out ----------------
__global__ void ln_kernel(const float* __restrict__ x, const float* __restrict__ g,
                          const float* __restrict__ b, bf16_t* __restrict__ y)
{
  const long row = blockIdx.x;
  const int tid = threadIdx.x;
  const float* xr = x + row * DMODEL;
  float v0 = xr[tid], v1 = xr[tid + 256], v2 = xr[tid + 512];
  float s  = v0 + v1 + v2;
  float ss = v0*v0 + v1*v1 + v2*v2;
  for (int o = 32; o; o >>= 1) { s += __shfl_down(s, o); ss += __shfl_down(ss, o); }
  __shared__ float rs[4], rss[4];
  const int wave = tid >> 6, lane = tid & 63;
  if (lane == 0) { rs[wave] = s; rss[wave] = ss; }
  __syncthreads();
  s  = rs[0] + rs[1] + rs[2] + rs[3];
  ss = rss[0] + rss[1] + rss[2] + rss[3];
  const float inv = 1.0f / (float)DMODEL;
  const float mean = s * inv;
  const float var  = ss * inv - mean * mean;
  const float rstd = rsqrtf(var + 1e-5f);
  bf16_t* yr = y + row * DMODEL;
  yr[tid]       = (bf16_t)(((v0 - mean) * rstd) * g[tid]       + b[tid]);
  yr[tid + 256] = (bf16_t)(((v1 - mean) * rstd) * g[tid + 256] + b[tid + 256]);
  yr[tid + 512] = (bf16_t)(((v2 - mean) * rstd) * g[tid + 512] + b[tid + 512]);
}

// ---------------- softmax over rows of 1024, in place, bf16 ----------------
__global__ void softmax_kernel(bf16_t* __restrict__ S)
{
  const long row = blockIdx.x;
  const int tid = threadIdx.x;
  bf16_t* p = S + row * SEQ + tid * 4;
  bf16x4 v = *(const bf16x4*)p;
  float f0 = (float)v[0], f1 = (float)v[1], f2 = (float)v[2], f3 = (float)v[3];
  float m = fmaxf(fmaxf(f0, f1), fmaxf(f2, f3));
  for (int o = 32; o; o >>= 1) m = fmaxf(m, __shfl_down(m, o));
  __shared__ float rm[4], rsum[4];
  const int wave = tid >> 6, lane = tid & 63;
  if (lane == 0) rm[wave] = m;
  __syncthreads();
  m = fmaxf(fmaxf(rm[0], rm[1]), fmaxf(rm[2], rm[3]));
  float e0 = __expf(f0 - m), e1 = __expf(f1 - m), e2 = __expf(f2 - m), e3 = __expf(f3 - m);
  float s = e0 + e1 + e2 + e3;
  for (int o = 32; o; o >>= 1) s += __shfl_down(s, o);
  if (lane == 0) rsum[wave] = s;
  __syncthreads();
  s = rsum[0] + rsum[1] + rsum[2] + rsum[3];
  const float invs = 1.0f / s;
  bf16x4 o4;
  o4[0] = (bf16_t)(e0 * invs); o4[1] = (bf16_t)(e1 * invs);
  o4[2] = (bf16_t)(e2 * invs); o4[3] = (bf16_t)(e3 * invs);
  *(bf16x4*)p = o4;
}

// ---------------- finalize (all fp32, in-place capable): o = acc + bias[col] + add ----------------
__global__ void finalize_f32(const float* __restrict__ acc, const float* __restrict__ add,
                             const float* __restrict__ bias, float* __restrict__ o)
{
  const long i = (long)blockIdx.x * 256 + threadIdx.x;
  const int c = (int)(i % DMODEL);
  o[i] = acc[i] + bias[c] + add[i];
}

// ---------------------------------------------------------------------------
extern "C" void kernel_launch(void* const* d_in, const int* in_sizes, int n_in,
                              void* d_out, int out_size, void* d_ws, size_t ws_size,
                              hipStream_t stream)
{
  (void)in_sizes; (void)n_in; (void)out_size;
  const float* x    = (const float*)d_in[0];
  const float* Wq   = (const float*)d_in[1];
  const float* Wk   = (const float*)d_in[2];
  const float* Wv   = (const float*)d_in[3];
  const float* Wu   = (const float*)d_in[4];
  const float* bu   = (const float*)d_in[5];
  const float* ln1g = (const float*)d_in[6];
  const float* ln1b = (const float*)d_in[7];
  const float* ln2g = (const float*)d_in[8];
  const float* ln2b = (const float*)d_in[9];
  const float* W1   = (const float*)d_in[10];
  const float* b1   = (const float*)d_in[11];
  const float* W2   = (const float*)d_in[12];
  const float* b2   = (const float*)d_in[13];
  float* out = (float*)d_out;

  char* ws = (char*)d_ws;
  size_t off = 0;
  auto alloc = [&](size_t bytes) -> void* {
    void* p = (void*)(ws + off);
    off += (bytes + 255) & ~(size_t)255;
    return p;
  };

  const float qk_alpha = 1.0f / sqrtf((float)DMODEL);
  dim3 tb(32, 8);

  if (ws_size >= (size_t)492e6) {
    // ================== FLAT PLAN (~488 MB) ==================
    bf16_t* WqT = (bf16_t*)alloc((size_t)DH * DMODEL * 2);
    bf16_t* WkT = (bf16_t*)alloc((size_t)DH * DMODEL * 2);
    bf16_t* WvT = (bf16_t*)alloc((size_t)DH * DMODEL * 2);
    bf16_t* WuT = (bf16_t*)alloc((size_t)DH * DMODEL * 2);
    bf16_t* W1T = (bf16_t*)alloc((size_t)DMODEL * DFF * 2);
    bf16_t* W2T = (bf16_t*)alloc((size_t)DMODEL * DFF * 2);
    bf16_t* y   = (bf16_t*)alloc((size_t)ROWS * DMODEL * 2);
    float*  x2  = (float* )alloc((size_t)ROWS * DMODEL * 4);
    bf16_t* Q   = (bf16_t*)alloc((size_t)ROWS * DH * 2);
    bf16_t* Kb  = (bf16_t*)alloc((size_t)ROWS * DH * 2);
    bf16_t* V   = (bf16_t*)alloc((size_t)ROWS * DH * 2);
    bf16_t* Vt  = (bf16_t*)alloc((size_t)ROWS * DH * 2);
    bf16_t* S   = (bf16_t*)alloc((size_t)NBATCH * NHEAD * SEQ * SEQ * 2);
    bf16_t* y2  = Q;     // reuse
    bf16_t* t   = Kb;    // reuse
    bf16_t* att = V;     // reuse

    transpose_f2b<<<dim3(DH/32, DMODEL/32), tb, 0, stream>>>(Wq, WqT, DH, DMODEL);
    transpose_f2b<<<dim3(DH/32, DMODEL/32), tb, 0, stream>>>(Wk, WkT, DH, DMODEL);
    transpose_f2b<<<dim3(DH/32, DMODEL/32), tb, 0, stream>>>(Wv, WvT, DH, DMODEL);
    transpose_f2b<<<dim3(DMODEL/32, DH/32), tb, 0, stream>>>(Wu, WuT, DMODEL, DH);
    transpose_f2b<<<dim3(DFF/32, DMODEL/32), tb, 0, stream>>>(W1, W1T, DFF, DMODEL);
    transpose_f2b<<<dim3(DMODEL/32, DFF/32), tb, 0, stream>>>(W2, W2T, DMODEL, DFF);
    ln_kernel<<<ROWS, 256, 0, stream>>>(x, ln1g, ln1b, y);

    gemm_bt<false,false,false,0><<<dim3(DH/128, ROWS/128, 1), 256, 0, stream>>>(
        y, WqT, Q, DMODEL, DMODEL, DMODEL, DH, 1, 0,0,0,0,0,0, nullptr, nullptr, 0, 1.0f);
    gemm_bt<false,false,false,0><<<dim3(DH/128, ROWS/128, 1), 256, 0, stream>>>(
        y, WkT, Kb, DMODEL, DMODEL, DMODEL, DH, 1, 0,0,0,0,0,0, nullptr, nullptr, 0, 1.0f);
    gemm_bt<false,false,false,0><<<dim3(DH/128, ROWS/128, 1), 256, 0, stream>>>(
        y, WvT, V, DMODEL, DMODEL, DMODEL, DH, 1, 0,0,0,0,0,0, nullptr, nullptr, 0, 1.0f);

    transpose_b<<<dim3(DMODEL/32, SEQ/32, NBATCH*NHEAD), tb, 0, stream>>>(
        V, Vt, DH, SEQ, NHEAD,
        (long)SEQ*DH, (long)DMODEL, (long)NHEAD*DMODEL*SEQ, (long)DMODEL*SEQ);

    gemm_bt<false,false,false,0><<<dim3(SEQ/128, SEQ/128, NBATCH*NHEAD), 256, 0, stream>>>(
        Q, Kb, S, DMODEL, DH, DH, SEQ, NHEAD,
        (long)SEQ*DH, (long)DMODEL, (long)SEQ*DH, (long)DMODEL,
        (long)NHEAD*SEQ*SEQ, (long)SEQ*SEQ, nullptr, nullptr, 0, qk_alpha);

    softmax_kernel<<<NBATCH*NHEAD*SEQ, 256, 0, stream>>>(S);

    gemm_bt<false,false,false,0><<<dim3(DMODEL/128, SEQ/128, NBATCH*NHEAD), 256, 0, stream>>>(
        S, Vt, att, SEQ, SEQ, SEQ, DH, NHEAD,
        (long)NHEAD*SEQ*SEQ, (long)SEQ*SEQ,
        (long)NHEAD*DMODEL*SEQ, (long)DMODEL*SEQ,
        (long)SEQ*DH, (long)DMODEL, nullptr, nullptr, 0, 1.0f);

    gemm_bt<true,true,false,1><<<dim3(DMODEL/128, ROWS/128, 1), 256, 0, stream>>>(
        att, WuT, x2, DH, DH, DH, DMODEL, 1, 0,0,0,0,0,0, bu, x, DMODEL, 1.0f);

    ln_kernel<<<ROWS, 256, 0, stream>>>(x2, ln2g, ln2b, y2);

    gemm_bt<true,false,true,0><<<dim3(DFF/128, ROWS/128, 1), 256, 0, stream>>>(
        y2, W1T, t, DMODEL, DMODEL, DMODEL, DFF, 1, 0,0,0,0,0,0, b1, nullptr, 0, 1.0f);

    gemm_bt<true,true,false,1><<<dim3(DMODEL/128, ROWS/128, 1), 256, 0, stream>>>(
        t, W2T, out, DFF, DFF, DFF, DMODEL, 1, 0,0,0,0,0,0, b2, x2, DMODEL, 1.0f);
  } else if (ws_size >= (size_t)75e6) {
    // ================== PER-HEAD PLAN (~73 MB) ==================
    bf16_t* W1T  = (bf16_t*)alloc((size_t)DMODEL * DFF * 2);
    bf16_t* W2T  = (bf16_t*)alloc((size_t)DMODEL * DFF * 2);
    bf16_t* y    = (bf16_t*)alloc((size_t)ROWS * DMODEL * 2);
    float*  x2f  = (float* )alloc((size_t)ROWS * DMODEL * 4);   // Wu accum; finalized in place
    bf16_t* WhT  = (bf16_t*)alloc((size_t)3 * DMODEL * DMODEL * 2);
    bf16_t* WuTh = (bf16_t*)alloc((size_t)DMODEL * DMODEL * 2);
    bf16_t* QKV  = (bf16_t*)alloc((size_t)ROWS * 3 * DMODEL * 2);
    bf16_t* Vt   = (bf16_t*)alloc((size_t)NBATCH * DMODEL * SEQ * 2);
    bf16_t* S    = (bf16_t*)alloc((size_t)NBATCH * SEQ * SEQ * 2);
    bf16_t* att  = (bf16_t*)alloc((size_t)ROWS * DMODEL * 2);
    bf16_t* t    = QKV;   // 25.17 MB spans QKV(18.87)+Vt(6.29) exactly
    bf16_t* y2   = S;

    transpose_f2b<<<dim3(DFF/32, DMODEL/32), tb, 0, stream>>>(W1, W1T, DFF, DMODEL);
    transpose_f2b<<<dim3(DMODEL/32, DFF/32), tb, 0, stream>>>(W2, W2T, DMODEL, DFF);
    ln_kernel<<<ROWS, 256, 0, stream>>>(x, ln1g, ln1b, y);

    const int N3 = 3 * DMODEL;
    for (int h = 0; h < NHEAD; ++h) {
      transpose_wh<<<dim3(24, 24, 4), tb, 0, stream>>>(Wq, Wk, Wv, Wu, WhT, WuTh, h);
      gemm_bt<false,false,false,0><<<dim3(N3/128, ROWS/128, 1), 256, 0, stream>>>(
          y, WhT, QKV, DMODEL, DMODEL, DMODEL, N3, 1, 0,0,0,0,0,0, nullptr, nullptr, 0, 1.0f);
      transpose_b<<<dim3(DMODEL/32, SEQ/32, NBATCH), tb, 0, stream>>>(
          QKV + 2*DMODEL, Vt, N3, SEQ, 1,
          (long)SEQ*N3, 0, (long)DMODEL*SEQ, 0);
      gemm_bt<false,false,false,0><<<dim3(SEQ/128, SEQ/128, NBATCH), 256, 0, stream>>>(
          QKV, QKV + DMODEL, S, DMODEL, N3, N3, SEQ, 1,
          (long)SEQ*N3, 0, (long)SEQ*N3, 0, (long)SEQ*SEQ, 0,
          nullptr, nullptr, 0, qk_alpha);
      softmax_kernel<<<NBATCH*SEQ, 256, 0, stream>>>(S);
      gemm_bt<false,false,false,0><<<dim3(DMODEL/128, SEQ/128, NBATCH), 256, 0, stream>>>(
          S, Vt, att, SEQ, SEQ, SEQ, DMODEL, 1,
          (long)SEQ*SEQ, 0, (long)DMODEL*SEQ, 0, (long)SEQ*DMODEL, 0,
          nullptr, nullptr, 0, 1.0f);
      if (h == 0)
        gemm_bt<false,false,false,1><<<dim3(DMODEL/128, ROWS/128, 1), 256, 0, stream>>>(
            att, WuTh, x2f, DMODEL, DMODEL, DMODEL, DMODEL, 1, 0,0,0,0,0,0,
            nullptr, nullptr, 0, 1.0f);
      else
        gemm_bt<false,false,false,2><<<dim3(DMODEL/128, ROWS/128, 1), 256, 0, stream>>>(
            att, WuTh, x2f, DMODEL, DMODEL, DMODEL, DMODEL, 1, 0,0,0,0,0,0,
            nullptr, nullptr, 0, 1.0f);
    }
    finalize_f32<<<(ROWS*DMODEL)/256, 256, 0, stream>>>(x2f, x, bu, x2f);  // in place
    ln_kernel<<<ROWS, 256, 0, stream>>>(x2f, ln2g, ln2b, y2);
    gemm_bt<true,false,true,0><<<dim3(DFF/128, ROWS/128, 1), 256, 0, stream>>>(
        y2, W1T, t, DMODEL, DMODEL, DMODEL, DFF, 1, 0,0,0,0,0,0, b1, nullptr, 0, 1.0f);
    gemm_bt<true,true,false,1><<<dim3(DMODEL/128, ROWS/128, 1), 256, 0, stream>>>(
        t, W2T, out, DFF, DFF, DFF, DMODEL, 1, 0,0,0,0,0,0, b2, x2f, DMODEL, 1.0f);
  } else {
    // ================== SMALL PLAN (~43 MB) ==================
    bf16_t* W1T   = (bf16_t*)alloc((size_t)DMODEL * DFF * 2);      // 4.72 MB
    bf16_t* W2T   = (bf16_t*)alloc((size_t)DMODEL * DFF * 2);      // 4.72 MB
    bf16_t* y     = (bf16_t*)alloc((size_t)ROWS * DMODEL * 2);     // 6.29 MB
    float*  x2f   = (float* )alloc((size_t)ROWS * DMODEL * 4);     // 12.58 MB, finalized in place
    char*   reg1  = (char*)alloc((size_t)3*DMODEL*DMODEL*2 + (size_t)DMODEL*DMODEL*2 + (size_t)SEQ*DMODEL*2);
    bf16_t* WhT   = (bf16_t*)reg1;
    bf16_t* WuTh  = (bf16_t*)(reg1 + (size_t)3*DMODEL*DMODEL*2);
    bf16_t* attb  = (bf16_t*)(reg1 + (size_t)4*DMODEL*DMODEL*2);
    bf16_t* y2    = (bf16_t*)reg1;                                  // MLP phase alias
    char*   reg2  = (char*)alloc((size_t)SEQ*3*DMODEL*2 + (size_t)DMODEL*SEQ*2 + (size_t)SEQ*SEQ*2);
    bf16_t* QKVb  = (bf16_t*)reg2;
    bf16_t* Vtb   = (bf16_t*)(reg2 + (size_t)SEQ*3*DMODEL*2);
    bf16_t* Sb    = (bf16_t*)(reg2 + (size_t)SEQ*3*DMODEL*2 + (size_t)DMODEL*SEQ*2);
    bf16_t* tslab = (bf16_t*)reg2;                                  // MLP phase alias

    transpose_f2b<<<dim3(DFF/32, DMODEL/32), tb, 0, stream>>>(W1, W1T, DFF, DMODEL);
    transpose_f2b<<<dim3(DMODEL/32, DFF/32), tb, 0, stream>>>(W2, W2T, DMODEL, DFF);
    ln_kernel<<<ROWS, 256, 0, stream>>>(x, ln1g, ln1b, y);

    const int N3 = 3 * DMODEL;
    for (int h = 0; h < NHEAD; ++h) {
      transpose_wh<<<dim3(24, 24, 4), tb, 0, stream>>>(Wq, Wk, Wv, Wu, WhT, WuTh, h);
      for (int b = 0; b < NBATCH; ++b) {
        const bf16_t* yb = y + (size_t)b * SEQ * DMODEL;
        gemm_bt<false,false,false,0><<<dim3(N3/128, SEQ/128, 1), 256, 0, stream>>>(
            yb, WhT, QKVb, DMODEL, DMODEL, DMODEL, N3, 1, 0,0,0,0,0,0,
            nullptr, nullptr, 0, 1.0f);
        transpose_b<<<dim3(DMODEL/32, SEQ/32, 1), tb, 0, stream>>>(
            QKVb + 2*DMODEL, Vtb, N3, SEQ, 1, 0,0,0,0);
        gemm_bt<false,false,false,0><<<dim3(SEQ/128, SEQ/128, 1), 256, 0, stream>>>(
            QKVb, QKVb + DMODEL, Sb, DMODEL, N3, N3, SEQ, 1, 0,0,0,0,0,0,
            nullptr, nullptr, 0, qk_alpha);
        softmax_kernel<<<SEQ, 256, 0, stream>>>(Sb);
        gemm_bt<false,false,false,0><<<dim3(DMODEL/128, SEQ/128, 1), 256, 0, stream>>>(
            Sb, Vtb, attb, SEQ, SEQ, SEQ, DMODEL, 1, 0,0,0,0,0,0,
            nullptr, nullptr, 0, 1.0f);
        float* x2b = x2f + (size_t)b * SEQ * DMODEL;
        if (h == 0)
          gemm_bt<false,false,false,1><<<dim3(DMODEL/128, SEQ/128, 1), 256, 0, stream>>>(
              attb, WuTh, x2b, DMODEL, DMODEL, DMODEL, DMODEL, 1, 0,0,0,0,0,0,
              nullptr, nullptr, 0, 1.0f);
        else
          gemm_bt<false,false,false,2><<<dim3(DMODEL/128, SEQ/128, 1), 256, 0, stream>>>(
              attb, WuTh, x2b, DMODEL, DMODEL, DMODEL, DMODEL, 1, 0,0,0,0,0,0,
              nullptr, nullptr, 0, 1.0f);
      }
    }
    finalize_f32<<<(ROWS*DMODEL)/256, 256, 0, stream>>>(x2f, x, bu, x2f);  // in place
    ln_kernel<<<ROWS, 256, 0, stream>>>(x2f, ln2g, ln2b, y2);
    // K-slab fused MLP: out = sum_kb relu(y2@W1[:,kb]+b1[kb]) @ W2[kb,:]  (+b2 +x2 on kb=0)
    for (int kb = 0; kb < 4; ++kb) {
      gemm_bt<true,false,true,0><<<dim3(DMODEL/128, ROWS/128, 1), 256, 0, stream>>>(
          y2, W1T + (size_t)kb*DMODEL*DMODEL, tslab, DMODEL, DMODEL, DMODEL, DMODEL, 1,
          0,0,0,0,0,0, b1 + kb*DMODEL, nullptr, 0, 1.0f);
      if (kb == 0)
        gemm_bt<true,true,false,1><<<dim3(DMODEL/128, ROWS/128, 1), 256, 0, stream>>>(
            tslab, W2T + (size_t)kb*DMODEL, out, DMODEL, DMODEL, DFF, DMODEL, 1,
            0,0,0,0,0,0, b2, x2f, DMODEL, 1.0f);
      else
        gemm_bt<false,false,false,2><<<dim3(DMODEL/128, ROWS/128, 1), 256, 0, stream>>>(
            tslab, W2T + (size_t)kb*DMODEL, out, DMODEL, DMODEL, DFF, DMODEL, 1,
            0,0,0,0,0,0, nullptr, nullptr, 0, 1.0f);
    }
  }
}